// Round 4
// baseline (438.292 us; speedup 1.0000x reference)
//
#include <hip/hip_runtime.h>
#include <math.h>
#include <stdint.h>

#define TL 128        // text length (m)
#define IL 100        // image length (n)
#define NP 112        // n padded (14 n-tiles of 8)
#define DIM 768
#define NSEQ 228
#define KT 32         // K chunk (floats per row per chunk)
#define NT 512        // 8 waves: 2 waves/SIMD
#define NWAVE 8
#define ITERS 50
// Staged row: 64 ushorts = 8 slots of 8 bf16. Slot s of row rr holds logical
// quad q where s = (q + rr + (rr>>3)) & 7; quads 0..3 = hi bf16, 4..7 = lo bf16.
// 8-slot rotation makes wave frag reads bank-balanced (each slot hit 8x/wave).

typedef float f32x4 __attribute__((ext_vector_type(4)));
typedef short short8 __attribute__((ext_vector_type(8)));

__device__ __forceinline__ uint16_t f2bf(float x) {
    union { float f; uint32_t u; } v; v.f = x;
    uint32_t r = v.u + 0x7FFFu + ((v.u >> 16) & 1u);   // RNE
    return (uint16_t)(r >> 16);
}
__device__ __forceinline__ float bf2f(uint16_t h) {
    union { float f; uint32_t u; } v; v.u = ((uint32_t)h) << 16;
    return v.f;
}

__device__ __forceinline__ float xorsum32(float x) {
    x += __shfl_xor(x, 1);
    x += __shfl_xor(x, 2);
    x += __shfl_xor(x, 4);
    x += __shfl_xor(x, 8);
    x += __shfl_xor(x, 16);
    return x;
}

// Barrier WITHOUT the vmcnt(0) drain __syncthreads() implies (m97 lesson: that
// drain serializes prefetch HBM latency into every chunk). Only LDS ordering is
// required at the chunk boundary; prefetch loads land in registers consumed by
// the issuing wave, so the compiler's own vmcnt waits before use suffice.
__device__ __forceinline__ void gemm_barrier() {
    __builtin_amdgcn_sched_barrier(0);
    asm volatile("s_waitcnt lgkmcnt(0)" ::: "memory");
    __builtin_amdgcn_s_barrier();
    __builtin_amdgcn_sched_barrier(0);
}

// Round-3 verified: 512 thr (2 waves/SIMD) dropped 204->165us, counters matched
// prediction. Round-4: kill the per-chunk vmcnt drain (48 full-drain barriers ->
// 24 lgkm-only barriers) via LDS double-buffered staging + raw barrier, and
// 2-deep global prefetch. IPOT phase unchanged from round 3.
__global__ void __launch_bounds__(NT, 2)
WRA_ot_kernel(const float* __restrict__ seq,
              const int* __restrict__ txt_pad,
              const int* __restrict__ img_pad,
              const int* __restrict__ is_correct,
              float* __restrict__ out, int nblocks)
{
    __shared__ __align__(16) union {
        uint16_t stg[2][240 * 64];   // 61440 B  dbuf staging: rows 0..127 X, 128..239 Y
        float As[448 * 32];          // 57344 B  raw dot, IPOT-owner layout (swizzled)
        float wp[2][7][TL];          // 7168 B   dbuf per-wave s[m] partials (IPOT loop)
    } u;
    __shared__ __align__(16) float sums[NSEQ];   // row sum-squares
    __shared__ __align__(16) float xm[TL];       // txt pad mask * 1e4
    __shared__ __align__(16) float ym[NP];       // img pad mask * 1e4
    __shared__ __align__(16) float inx[TL];      // inv norms
    __shared__ __align__(16) float iny[NP];
    __shared__ float red[NWAVE];
    __shared__ int cnt[2];
    // LDS total: 61440+912+512+448+512+448+32+8 = 64312 B <= 64 KiB

    const int t    = threadIdx.x;
    const int b    = blockIdx.x;
    const int w    = t >> 6;
    const int lane = t & 63;

    // ---- phase 0: masks & lengths ----
    if (t < 2) cnt[t] = 0;
    if (t < NSEQ) sums[t] = 0.0f;
    __syncthreads();
    if (t < TL) {
        int p = txt_pad[b * TL + t] ? 1 : 0;
        xm[t] = p ? 1e4f : 0.0f;
        if (p) atomicAdd(&cnt[0], 1);
    } else if (t < TL + IL) {
        int p = img_pad[b * IL + (t - TL)] ? 1 : 0;
        ym[t - TL] = p ? 1e4f : 0.0f;
        if (p) atomicAdd(&cnt[1], 1);
    } else if (t < TL + NP) {
        ym[t - TL] = 1e4f;   // fake n = 100..111
    }

    // ---- GEMM: raw dot D[m,n] = sum_k X[m,k] Y[n,k] via split-bf16 MFMA ----
    const float* Xg = seq + (size_t)b * NSEQ * DIM;   // text rows 0..127
    const float* Yg = Xg + (size_t)TL * DIM;          // img rows 0..99

    // staging slots: 1824 float4 per chunk, slot f = t + 512*r (r<4)
    const float* gp[4];
    int   off_hi[4];    // ushort offset within one staging buffer (hi half-quad)
    int   srow[4];
    bool  act[4];
    float nrm[4];
#pragma unroll
    for (int r = 0; r < 4; r++) {
        int f = t + NT * r;
        act[r] = (f < 1824);
        nrm[r] = 0.0f;
        int f2 = act[r] ? f : 0;
        bool isX = (f2 < 1024);
        int row = isX ? (f2 >> 3) : ((f2 - 1024) >> 3);
        int kc  = (f2 & 7) << 2;                  // k offset 0..28 (floats)
        gp[r] = (isX ? Xg : Yg) + row * DIM + kc;
        int rr = isX ? row : (TL + row);          // unified staging row 0..227
        srow[r] = rr;
        int q = (f2 & 7) >> 1;                    // logical hi quad 0..3
        int h = f2 & 1;                           // 8B half within quad
        int s = (q + rr + (rr >> 3)) & 7;         // physical slot (rotation)
        off_hi[r] = rr * 64 + 8 * s + 4 * h;      // lo half lives at off_hi ^ 32
    }
    {   // zero Y pad rows 100..111 (staging rows 228..239) in BOTH parities
        uint32_t* s32 = (uint32_t*)&u.stg[0][0];
        for (int i = t; i < 384 * 2; i += NT) {
            int par = (i < 384) ? 0 : 1;
            int off = i - par * 384;
            s32[par * 7680 + 228 * 32 + off] = 0;
        }
    }

    // wave tiling: wm = w>>1 owns m-tiles {2wm, 2wm+1}; wn = w&1 owns n-tiles 4wn..
    const int wm = w >> 1;
    const int wn = w & 1;
    const int NQ = wn ? 3 : 4;        // n-tiles 0..3 | 4..6
    f32x4 acc[2][4];
#pragma unroll
    for (int a = 0; a < 2; a++)
#pragma unroll
        for (int q = 0; q < 4; q++) acc[a][q] = (f32x4){0.f, 0.f, 0.f, 0.f};

    const int lr = lane & 15, lq = lane >> 4;

    // convert+store one chunk's worth of data into staging parity `par`
    auto convert_store = [&](const float4* vv, int par) {
        uint16_t* base = &u.stg[par][0];
#pragma unroll
        for (int r = 0; r < 4; r++) if (act[r]) {
            float4 x = vv[r];
            nrm[r] += x.x*x.x + x.y*x.y + x.z*x.z + x.w*x.w;
            uint16_t h0 = f2bf(x.x), h1 = f2bf(x.y), h2 = f2bf(x.z), h3 = f2bf(x.w);
            uint16_t l0 = f2bf(x.x - bf2f(h0)), l1 = f2bf(x.y - bf2f(h1));
            uint16_t l2 = f2bf(x.z - bf2f(h2)), l3 = f2bf(x.w - bf2f(h3));
            uint64_t hq  = (uint64_t)h0 | ((uint64_t)h1<<16) | ((uint64_t)h2<<32) | ((uint64_t)h3<<48);
            uint64_t lq8 = (uint64_t)l0 | ((uint64_t)l1<<16) | ((uint64_t)l2<<32) | ((uint64_t)l3<<48);
            *(uint64_t*)(base + off_hi[r])        = hq;
            *(uint64_t*)(base + (off_hi[r] ^ 32)) = lq8;
        }
    };

    // prologue: chunk0 -> buf0; chunks 1,2 in flight (2-deep prefetch)
    float4 va[4], vb[4];
#pragma unroll
    for (int r = 0; r < 4; r++) if (act[r]) va[r] = *(const float4*)(gp[r]);
#pragma unroll
    for (int r = 0; r < 4; r++) if (act[r]) vb[r] = *(const float4*)(gp[r] + KT);
    convert_store(va, 0);
#pragma unroll
    for (int r = 0; r < 4; r++) if (act[r]) va[r] = *(const float4*)(gp[r] + 2 * KT);
    gemm_barrier();   // buf0 ready (also covers zero-pad + phase-0 LDS writes)

    for (int c = 0; c < 24; c++) {
        const int p = c & 1;
        if (c < 23) {
            // chunk c+1 lives in v[(c+1)&1]: c even -> vb, c odd -> va
            convert_store((c & 1) ? va : vb, p ^ 1);
            if (c < 21) {   // refill that slot with chunk c+3 (consumed at loop c+2)
                float4* vv = (c & 1) ? va : vb;
#pragma unroll
                for (int r = 0; r < 4; r++) if (act[r])
                    vv[r] = *(const float4*)(gp[r] + (c + 3) * KT);
            }
        }
        // frag reads + MFMA from buf p
        const uint16_t* base = &u.stg[p][0];
        short8 ah[2], al[2], bh[4], bl[4];
#pragma unroll
        for (int a = 0; a < 2; a++) {
            int m = 16 * (2*wm + a) + lr;
            int s = (lq + m + (m >> 3)) & 7;
            int ao = m * 64 + 8 * s;
            ah[a] = *(const short8*)(base + ao);
            al[a] = *(const short8*)(base + (ao ^ 32));
        }
#pragma unroll
        for (int q = 0; q < 4; q++) if (q < NQ) {
            int n  = 16 * (4*wn + q) + lr;
            int rr = TL + n;
            int s  = (lq + rr + (rr >> 3)) & 7;
            int bo = rr * 64 + 8 * s;
            bh[q] = *(const short8*)(base + bo);
            bl[q] = *(const short8*)(base + (bo ^ 32));
        }
#pragma unroll
        for (int a = 0; a < 2; a++)
#pragma unroll
            for (int q = 0; q < 4; q++) if (q < NQ) {
                acc[a][q] = __builtin_amdgcn_mfma_f32_16x16x32_bf16(ah[a], bh[q], acc[a][q], 0, 0, 0);
                acc[a][q] = __builtin_amdgcn_mfma_f32_16x16x32_bf16(ah[a], bl[q], acc[a][q], 0, 0, 0);
                acc[a][q] = __builtin_amdgcn_mfma_f32_16x16x32_bf16(al[a], bh[q], acc[a][q], 0, 0, 0);
            }
        gemm_barrier();   // one barrier per chunk; prefetch stays in flight
    }

    // (final gemm_barrier drained all frag reads -> safe to overwrite stg)
#pragma unroll
    for (int r = 0; r < 4; r++) if (act[r]) atomicAdd(&sums[srow[r]], nrm[r]);
    // scatter raw dots into IPOT-owner layout: owner tp = (m>>2) + 32*(n>>3);
    // cell XOR-swizzled by (tp&7) so init ds_read_b128 is bank-balanced.
#pragma unroll
    for (int a = 0; a < 2; a++)
#pragma unroll
        for (int q = 0; q < 4; q++) if (q < NQ)
#pragma unroll
            for (int rg = 0; rg < 4; rg++) {
                int m = 16 * (2*wm + a) + 4*lq + rg;   // D row = quad*4+reg
                int n = 16 * (4*wn + q) + lr;          // D col = lane&15
                int tp = (m >> 2) + ((n >> 3) << 5);
                int cell = (((n & 7) ^ (tp & 7)) << 2) + (m & 3);
                u.As[(tp << 5) + cell] = acc[a][q][rg];
            }
    __syncthreads();
    if (t < TL)            inx[t]      = 1.0f / fmaxf(sqrtf(sums[t]), 1e-5f);
    else if (t < NSEQ)     iny[t - TL] = 1.0f / fmaxf(sqrtf(sums[t]), 1e-5f);
    else if (t < TL + NP)  iny[t - TL] = 1.0f;
    __syncthreads();

    // ---- IPOT: thread (mI, nI) owns m = 4mI..+3, n = 8nI..+7, all in regs ----
    const float xlen = (float)(TL - cnt[0]);
    const float ylen = (float)(IL - cnt[1]);
    const int mI = lane & 31;            // == t & 31
    const int nI = t >> 5;               // 0..15; active < 14 (waves 0..6)
    const bool activeN = (nI < 14);

    float rx[4], xmv[4], ry[8], ymv[8];
    {
        float4 a0 = *(const float4*)&inx[4*mI];
        rx[0]=a0.x; rx[1]=a0.y; rx[2]=a0.z; rx[3]=a0.w;
        float4 b0 = *(const float4*)&xm[4*mI];
        xmv[0]=b0.x; xmv[1]=b0.y; xmv[2]=b0.z; xmv[3]=b0.w;
        if (activeN) {
            float4 c0 = *(const float4*)&iny[8*nI], c1 = *(const float4*)&iny[8*nI + 4];
            ry[0]=c0.x; ry[1]=c0.y; ry[2]=c0.z; ry[3]=c0.w;
            ry[4]=c1.x; ry[5]=c1.y; ry[6]=c1.z; ry[7]=c1.w;
            float4 d0 = *(const float4*)&ym[8*nI], d1 = *(const float4*)&ym[8*nI + 4];
            ymv[0]=d0.x; ymv[1]=d0.y; ymv[2]=d0.z; ymv[3]=d0.w;
            ymv[4]=d1.x; ymv[5]=d1.y; ymv[6]=d1.z; ymv[7]=d1.w;
        } else {
#pragma unroll
            for (int j = 0; j < 8; j++) { ry[j] = 1.0f; ymv[j] = 1e4f; }
        }
    }

    float aa[8][4], qq[8][4];   // [j = n][i = m]
    if (activeN) {
#pragma unroll
        for (int j = 0; j < 8; j++) {
            float4 d0 = *(const float4*)&u.As[(t << 5) + ((j ^ (t & 7)) << 2)];
            float dv[4] = {d0.x, d0.y, d0.z, d0.w};
#pragma unroll
            for (int i = 0; i < 4; i++) {
                bool pad = (xmv[i] > 0.0f) || (ymv[j] > 0.0f);
                float cc = pad ? 0.0f : (1.0f - dv[i] * rx[i] * ry[j]);
                float av = pad ? 0.0f : expf(-2.0f * cc);
                aa[j][i] = av; qq[j][i] = av;
            }
        }
    } else {
#pragma unroll
        for (int j = 0; j < 8; j++)
#pragma unroll
            for (int i = 0; i < 4; i++) { aa[j][i] = 0.0f; qq[j][i] = 0.0f; }
    }
    __syncthreads();   // As reads done before wp (union overlay) is first written

    float sg[4];
#pragma unroll
    for (int i = 0; i < 4; i++) sg[i] = (xmv[i] > 0.0f) ? 0.0f : (1.0f / xlen);

    float dl[8];
    for (int it = 0; it < ITERS; ++it) {
        // qs[n] = sum_m Q sigma : in-thread 4m, butterfly over 32 mI lanes
#pragma unroll
        for (int j = 0; j < 8; j++) {
            float pj = qq[j][0]*sg[0] + qq[j][1]*sg[1] + qq[j][2]*sg[2] + qq[j][3]*sg[3];
            pj = xorsum32(pj);
            dl[j] = __builtin_amdgcn_rcpf(ylen * pj + ymv[j]);
        }
        // s[m] = sum_n delta*Q : in-thread 8n, shfl across nI halves, LDS cross-wave
        float sp[4];
#pragma unroll
        for (int i = 0; i < 4; i++) {
            float s = dl[0]*qq[0][i] + dl[1]*qq[1][i] + dl[2]*qq[2][i] + dl[3]*qq[3][i]
                    + dl[4]*qq[4][i] + dl[5]*qq[5][i] + dl[6]*qq[6][i] + dl[7]*qq[7][i];
            sp[i] = s + __shfl_xor(s, 32);   // combine the wave's two nI groups
        }
        if (w < 7 && lane < 32) {
            *(float4*)&u.wp[it & 1][w][4 * mI] = make_float4(sp[0], sp[1], sp[2], sp[3]);
        }
        __syncthreads();   // the ONLY barrier per iteration (wp double-buffered)
        {
            float4 s0 = *(const float4*)&u.wp[it & 1][0][4*mI];
            float4 s1 = *(const float4*)&u.wp[it & 1][1][4*mI];
            float4 s2 = *(const float4*)&u.wp[it & 1][2][4*mI];
            float4 s3 = *(const float4*)&u.wp[it & 1][3][4*mI];
            float4 s4 = *(const float4*)&u.wp[it & 1][4][4*mI];
            float4 s5 = *(const float4*)&u.wp[it & 1][5][4*mI];
            float4 s6 = *(const float4*)&u.wp[it & 1][6][4*mI];
            float t0 = s0.x+s1.x+s2.x+s3.x+s4.x+s5.x+s6.x;
            float t1 = s0.y+s1.y+s2.y+s3.y+s4.y+s5.y+s6.y;
            float t2 = s0.z+s1.z+s2.z+s3.z+s4.z+s5.z+s6.z;
            float t3 = s0.w+s1.w+s2.w+s3.w+s4.w+s5.w+s6.w;
            sg[0] = __builtin_amdgcn_rcpf(xlen*t0 + xmv[0]);
            sg[1] = __builtin_amdgcn_rcpf(xlen*t1 + xmv[1]);
            sg[2] = __builtin_amdgcn_rcpf(xlen*t2 + xmv[2]);
            sg[3] = __builtin_amdgcn_rcpf(xlen*t3 + xmv[3]);
        }
        if (it < ITERS - 1) {
#pragma unroll
            for (int j = 0; j < 8; j++) {
                float dj = dl[j];
#pragma unroll
                for (int i = 0; i < 4; i++)
                    qq[j][i] = (qq[j][i] * aa[j][i]) * (dj * sg[i]);
            }
        }
    }

    // ot = sum C^T (.) T_50 ;  c = -0.5*ln(a) on non-pad entries
    float local = 0.0f;
#pragma unroll
    for (int j = 0; j < 8; j++)
#pragma unroll
        for (int i = 0; i < 4; i++) {
            float av = aa[j][i];
            float cc = (av > 0.0f) ? (-0.5f * logf(av)) : 0.0f;
            local += cc * qq[j][i] * (dl[j] * sg[i]);
        }
    local = xorsum32(local);
    local += __shfl_xor(local, 32);
    if (lane == 0) red[w] = local;
    __syncthreads();
    if (t == 0) {
        float tot = red[0] + red[1] + red[2] + red[3] + red[4] + red[5] + red[6] + red[7];
        float sgn = (is_correct[b] == 1) ? 1.0f : -1.0f;
        atomicAdd(out, sgn * tot / (float)nblocks);
    }
}

extern "C" void kernel_launch(void* const* d_in, const int* in_sizes, int n_in,
                              void* d_out, int out_size, void* d_ws, size_t ws_size,
                              hipStream_t stream) {
    const float* seq   = (const float*)d_in[0];
    const int* txt_pad = (const int*)d_in[3];
    const int* img_pad = (const int*)d_in[4];
    const int* is_corr = (const int*)d_in[5];
    float* out = (float*)d_out;
    const int B = in_sizes[5];

    hipMemsetAsync(out, 0, sizeof(float), stream);
    WRA_ot_kernel<<<B, NT, 0, stream>>>(seq, txt_pad, img_pad, is_corr, out, B);
}

// Round 5
// 374.936 us; speedup vs baseline: 1.1690x; 1.1690x over previous
//
#include <hip/hip_runtime.h>
#include <math.h>
#include <stdint.h>

#define TL 128        // text length (m)
#define IL 100        // image length (n)
#define NP 112        // n padded (14 n-tiles of 8)
#define DIM 768
#define NSEQ 228
#define KT 32         // K chunk (floats per row per chunk)
#define NT 512        // 8 waves: 2 waves/SIMD
#define NWAVE 8
#define ITERS 50
// Staged row: 64 ushorts = 8 slots of 8 bf16. Slot s of row rr holds logical
// quad q where s = (q + rr + (rr>>3)) & 7; quads 0..3 = hi bf16, 4..7 = lo bf16.
// 8-slot rotation makes wave frag reads bank-balanced (each slot hit 8x/wave).

typedef float f32x4 __attribute__((ext_vector_type(4)));
typedef short short8 __attribute__((ext_vector_type(8)));

__device__ __forceinline__ uint16_t f2bf(float x) {
    union { float f; uint32_t u; } v; v.f = x;
    uint32_t r = v.u + 0x7FFFu + ((v.u >> 16) & 1u);   // RNE
    return (uint16_t)(r >> 16);
}
__device__ __forceinline__ float bf2f(uint16_t h) {
    union { float f; uint32_t u; } v; v.u = ((uint32_t)h) << 16;
    return v.f;
}

__device__ __forceinline__ float xorsum32(float x) {
    x += __shfl_xor(x, 1);
    x += __shfl_xor(x, 2);
    x += __shfl_xor(x, 4);
    x += __shfl_xor(x, 8);
    x += __shfl_xor(x, 16);
    return x;
}

// Barrier WITHOUT the vmcnt(0) drain __syncthreads() implies (m97 lesson: that
// drain serializes prefetch HBM latency into every chunk). Only LDS ordering is
// required at the chunk boundary; prefetch loads land in registers consumed by
// the issuing wave, so the compiler's own vmcnt waits before use suffice.
__device__ __forceinline__ void gemm_barrier() {
    __builtin_amdgcn_sched_barrier(0);
    asm volatile("s_waitcnt lgkmcnt(0)" ::: "memory");
    __builtin_amdgcn_s_barrier();
    __builtin_amdgcn_sched_barrier(0);
}

// Round-4 post-mortem: convert_store((c&1)?va:vb) formed a runtime pointer to
// register arrays -> va/vb demoted to scratch -> 162 MB HBM WRITE_SIZE, 228us.
// Round-5: unroll chunk loop x2 so buffer selection is COMPILE-TIME; the
// convert-store body is a macro over a NAMED array (no address ever formed).
#define CONVERT_STORE(vv, par) do {                                            \
    uint16_t* base_ = &u.stg[par][0];                                          \
    _Pragma("unroll")                                                          \
    for (int r = 0; r < 4; r++) if (act[r]) {                                  \
        float4 x = vv[r];                                                      \
        nrm[r] += x.x*x.x + x.y*x.y + x.z*x.z + x.w*x.w;                       \
        uint16_t h0 = f2bf(x.x), h1 = f2bf(x.y), h2 = f2bf(x.z), h3 = f2bf(x.w); \
        uint16_t l0 = f2bf(x.x - bf2f(h0)), l1 = f2bf(x.y - bf2f(h1));         \
        uint16_t l2 = f2bf(x.z - bf2f(h2)), l3 = f2bf(x.w - bf2f(h3));         \
        uint64_t hq  = (uint64_t)h0 | ((uint64_t)h1<<16) | ((uint64_t)h2<<32) | ((uint64_t)h3<<48); \
        uint64_t lq8 = (uint64_t)l0 | ((uint64_t)l1<<16) | ((uint64_t)l2<<32) | ((uint64_t)l3<<48); \
        *(uint64_t*)(base_ + off_hi[r])        = hq;                           \
        *(uint64_t*)(base_ + (off_hi[r] ^ 32)) = lq8;                          \
    }                                                                          \
} while (0)

#define PREFETCH(vv, cidx) do {                                                \
    _Pragma("unroll")                                                          \
    for (int r = 0; r < 4; r++) if (act[r])                                    \
        vv[r] = *(const float4*)(gp[r] + (cidx) * KT);                         \
} while (0)

#define MFMA_CHUNK(par) do {                                                   \
    const uint16_t* base_ = &u.stg[par][0];                                    \
    short8 ah[2], al[2], bh[4], bl[4];                                         \
    _Pragma("unroll")                                                          \
    for (int a = 0; a < 2; a++) {                                              \
        int m = 16 * (2*wm + a) + lr;                                          \
        int s = (lq + m + (m >> 3)) & 7;                                       \
        int ao = m * 64 + 8 * s;                                               \
        ah[a] = *(const short8*)(base_ + ao);                                  \
        al[a] = *(const short8*)(base_ + (ao ^ 32));                           \
    }                                                                          \
    _Pragma("unroll")                                                          \
    for (int q = 0; q < 4; q++) if (q < NQ) {                                  \
        int n  = 16 * (4*wn + q) + lr;                                         \
        int rr = TL + n;                                                       \
        int s  = (lq + rr + (rr >> 3)) & 7;                                    \
        int bo = rr * 64 + 8 * s;                                              \
        bh[q] = *(const short8*)(base_ + bo);                                  \
        bl[q] = *(const short8*)(base_ + (bo ^ 32));                           \
    }                                                                          \
    _Pragma("unroll")                                                          \
    for (int a = 0; a < 2; a++)                                                \
        _Pragma("unroll")                                                      \
        for (int q = 0; q < 4; q++) if (q < NQ) {                              \
            acc[a][q] = __builtin_amdgcn_mfma_f32_16x16x32_bf16(ah[a], bh[q], acc[a][q], 0, 0, 0); \
            acc[a][q] = __builtin_amdgcn_mfma_f32_16x16x32_bf16(ah[a], bl[q], acc[a][q], 0, 0, 0); \
            acc[a][q] = __builtin_amdgcn_mfma_f32_16x16x32_bf16(al[a], bh[q], acc[a][q], 0, 0, 0); \
        }                                                                      \
} while (0)

__global__ void __launch_bounds__(NT, 2)
WRA_ot_kernel(const float* __restrict__ seq,
              const int* __restrict__ txt_pad,
              const int* __restrict__ img_pad,
              const int* __restrict__ is_correct,
              float* __restrict__ out, int nblocks)
{
    __shared__ __align__(16) union {
        uint16_t stg[2][240 * 64];   // 61440 B  dbuf staging: rows 0..127 X, 128..239 Y
        float As[448 * 32];          // 57344 B  raw dot, IPOT-owner layout (swizzled)
        float wp[2][7][TL];          // 7168 B   dbuf per-wave s[m] partials (IPOT loop)
    } u;
    __shared__ __align__(16) float sums[NSEQ];   // row sum-squares
    __shared__ __align__(16) float xm[TL];       // txt pad mask * 1e4
    __shared__ __align__(16) float ym[NP];       // img pad mask * 1e4
    __shared__ __align__(16) float inx[TL];      // inv norms
    __shared__ __align__(16) float iny[NP];
    __shared__ float red[NWAVE];
    __shared__ int cnt[2];
    // LDS total: 61440+912+512+448+512+448+32+8 = 64312 B <= 64 KiB

    const int t    = threadIdx.x;
    const int b    = blockIdx.x;
    const int w    = t >> 6;
    const int lane = t & 63;

    // ---- phase 0: masks & lengths ----
    if (t < 2) cnt[t] = 0;
    if (t < NSEQ) sums[t] = 0.0f;
    __syncthreads();
    if (t < TL) {
        int p = txt_pad[b * TL + t] ? 1 : 0;
        xm[t] = p ? 1e4f : 0.0f;
        if (p) atomicAdd(&cnt[0], 1);
    } else if (t < TL + IL) {
        int p = img_pad[b * IL + (t - TL)] ? 1 : 0;
        ym[t - TL] = p ? 1e4f : 0.0f;
        if (p) atomicAdd(&cnt[1], 1);
    } else if (t < TL + NP) {
        ym[t - TL] = 1e4f;   // fake n = 100..111
    }

    // ---- GEMM: raw dot D[m,n] = sum_k X[m,k] Y[n,k] via split-bf16 MFMA ----
    const float* Xg = seq + (size_t)b * NSEQ * DIM;   // text rows 0..127
    const float* Yg = Xg + (size_t)TL * DIM;          // img rows 0..99

    // staging slots: 1824 float4 per chunk, slot f = t + 512*r (r<4)
    const float* gp[4];
    int   off_hi[4];    // ushort offset within one staging buffer (hi half-quad)
    int   srow[4];
    bool  act[4];
    float nrm[4];
#pragma unroll
    for (int r = 0; r < 4; r++) {
        int f = t + NT * r;
        act[r] = (f < 1824);
        nrm[r] = 0.0f;
        int f2 = act[r] ? f : 0;
        bool isX = (f2 < 1024);
        int row = isX ? (f2 >> 3) : ((f2 - 1024) >> 3);
        int kc  = (f2 & 7) << 2;                  // k offset 0..28 (floats)
        gp[r] = (isX ? Xg : Yg) + row * DIM + kc;
        int rr = isX ? row : (TL + row);          // unified staging row 0..227
        srow[r] = rr;
        int q = (f2 & 7) >> 1;                    // logical hi quad 0..3
        int h = f2 & 1;                           // 8B half within quad
        int s = (q + rr + (rr >> 3)) & 7;         // physical slot (rotation)
        off_hi[r] = rr * 64 + 8 * s + 4 * h;      // lo half lives at off_hi ^ 32
    }
    {   // zero Y pad rows 100..111 (staging rows 228..239) in BOTH parities
        uint32_t* s32 = (uint32_t*)&u.stg[0][0];
        for (int i = t; i < 384 * 2; i += NT) {
            int par = (i < 384) ? 0 : 1;
            int off = i - par * 384;
            s32[par * 7680 + 228 * 32 + off] = 0;
        }
    }

    // wave tiling: wm = w>>1 owns m-tiles {2wm, 2wm+1}; wn = w&1 owns n-tiles 4wn..
    const int wm = w >> 1;
    const int wn = w & 1;
    const int NQ = wn ? 3 : 4;        // n-tiles 0..3 | 4..6
    f32x4 acc[2][4];
#pragma unroll
    for (int a = 0; a < 2; a++)
#pragma unroll
        for (int q = 0; q < 4; q++) acc[a][q] = (f32x4){0.f, 0.f, 0.f, 0.f};

    const int lr = lane & 15, lq = lane >> 4;

    // prologue: chunk0 -> buf0 (from va); vb holds chunk1; va refilled w/ chunk2
    float4 va[4], vb[4];
    PREFETCH(va, 0);
    PREFETCH(vb, 1);
    CONVERT_STORE(va, 0);
    PREFETCH(va, 2);
    gemm_barrier();   // buf0 ready (also covers zero-pad + phase-0 LDS writes)

    // steady state, UNROLLED x2 so buffer/array selection is compile-time:
    //  even chunk cc  : consume buf0, store vb->buf1, refill vb with cc+3
    //  odd  chunk cc+1: consume buf1, store va->buf0, refill va with cc+4
#pragma unroll 1
    for (int cc = 0; cc < 24; cc += 2) {
        {   // chunk cc (even, buf0; chunk cc+1 data sits in vb)
            if (cc < 23) {
                CONVERT_STORE(vb, 1);
                if (cc < 21) PREFETCH(vb, cc + 3);
            }
            MFMA_CHUNK(0);
            gemm_barrier();
        }
        {   // chunk cc+1 (odd, buf1; chunk cc+2 data sits in va)
            if (cc + 1 < 23) {
                CONVERT_STORE(va, 0);
                if (cc + 1 < 21) PREFETCH(va, cc + 4);
            }
            MFMA_CHUNK(1);
            gemm_barrier();
        }
    }

    // (final gemm_barrier drained all frag reads -> safe to overwrite stg)
#pragma unroll
    for (int r = 0; r < 4; r++) if (act[r]) atomicAdd(&sums[srow[r]], nrm[r]);
    // scatter raw dots into IPOT-owner layout: owner tp = (m>>2) + 32*(n>>3);
    // cell XOR-swizzled by (tp&7) so init ds_read_b128 is bank-balanced.
#pragma unroll
    for (int a = 0; a < 2; a++)
#pragma unroll
        for (int q = 0; q < 4; q++) if (q < NQ)
#pragma unroll
            for (int rg = 0; rg < 4; rg++) {
                int m = 16 * (2*wm + a) + 4*lq + rg;   // D row = quad*4+reg
                int n = 16 * (4*wn + q) + lr;          // D col = lane&15
                int tp = (m >> 2) + ((n >> 3) << 5);
                int cell = (((n & 7) ^ (tp & 7)) << 2) + (m & 3);
                u.As[(tp << 5) + cell] = acc[a][q][rg];
            }
    __syncthreads();
    if (t < TL)            inx[t]      = 1.0f / fmaxf(sqrtf(sums[t]), 1e-5f);
    else if (t < NSEQ)     iny[t - TL] = 1.0f / fmaxf(sqrtf(sums[t]), 1e-5f);
    else if (t < TL + NP)  iny[t - TL] = 1.0f;
    __syncthreads();

    // ---- IPOT: thread (mI, nI) owns m = 4mI..+3, n = 8nI..+7, all in regs ----
    const float xlen = (float)(TL - cnt[0]);
    const float ylen = (float)(IL - cnt[1]);
    const int mI = lane & 31;            // == t & 31
    const int nI = t >> 5;               // 0..15; active < 14 (waves 0..6)
    const bool activeN = (nI < 14);

    float rx[4], xmv[4], ry[8], ymv[8];
    {
        float4 a0 = *(const float4*)&inx[4*mI];
        rx[0]=a0.x; rx[1]=a0.y; rx[2]=a0.z; rx[3]=a0.w;
        float4 b0 = *(const float4*)&xm[4*mI];
        xmv[0]=b0.x; xmv[1]=b0.y; xmv[2]=b0.z; xmv[3]=b0.w;
        if (activeN) {
            float4 c0 = *(const float4*)&iny[8*nI], c1 = *(const float4*)&iny[8*nI + 4];
            ry[0]=c0.x; ry[1]=c0.y; ry[2]=c0.z; ry[3]=c0.w;
            ry[4]=c1.x; ry[5]=c1.y; ry[6]=c1.z; ry[7]=c1.w;
            float4 d0 = *(const float4*)&ym[8*nI], d1 = *(const float4*)&ym[8*nI + 4];
            ymv[0]=d0.x; ymv[1]=d0.y; ymv[2]=d0.z; ymv[3]=d0.w;
            ymv[4]=d1.x; ymv[5]=d1.y; ymv[6]=d1.z; ymv[7]=d1.w;
        } else {
#pragma unroll
            for (int j = 0; j < 8; j++) { ry[j] = 1.0f; ymv[j] = 1e4f; }
        }
    }

    float aa[8][4], qq[8][4];   // [j = n][i = m]
    if (activeN) {
#pragma unroll
        for (int j = 0; j < 8; j++) {
            float4 d0 = *(const float4*)&u.As[(t << 5) + ((j ^ (t & 7)) << 2)];
            float dv[4] = {d0.x, d0.y, d0.z, d0.w};
#pragma unroll
            for (int i = 0; i < 4; i++) {
                bool pad = (xmv[i] > 0.0f) || (ymv[j] > 0.0f);
                float cc = pad ? 0.0f : (1.0f - dv[i] * rx[i] * ry[j]);
                float av = pad ? 0.0f : expf(-2.0f * cc);
                aa[j][i] = av; qq[j][i] = av;
            }
        }
    } else {
#pragma unroll
        for (int j = 0; j < 8; j++)
#pragma unroll
            for (int i = 0; i < 4; i++) { aa[j][i] = 0.0f; qq[j][i] = 0.0f; }
    }
    __syncthreads();   // As reads done before wp (union overlay) is first written

    float sg[4];
#pragma unroll
    for (int i = 0; i < 4; i++) sg[i] = (xmv[i] > 0.0f) ? 0.0f : (1.0f / xlen);

    float dl[8];
    for (int it = 0; it < ITERS; ++it) {
        // qs[n] = sum_m Q sigma : in-thread 4m, butterfly over 32 mI lanes
#pragma unroll
        for (int j = 0; j < 8; j++) {
            float pj = qq[j][0]*sg[0] + qq[j][1]*sg[1] + qq[j][2]*sg[2] + qq[j][3]*sg[3];
            pj = xorsum32(pj);
            dl[j] = __builtin_amdgcn_rcpf(ylen * pj + ymv[j]);
        }
        // s[m] = sum_n delta*Q : in-thread 8n, shfl across nI halves, LDS cross-wave
        float sp[4];
#pragma unroll
        for (int i = 0; i < 4; i++) {
            float s = dl[0]*qq[0][i] + dl[1]*qq[1][i] + dl[2]*qq[2][i] + dl[3]*qq[3][i]
                    + dl[4]*qq[4][i] + dl[5]*qq[5][i] + dl[6]*qq[6][i] + dl[7]*qq[7][i];
            sp[i] = s + __shfl_xor(s, 32);   // combine the wave's two nI groups
        }
        if (w < 7 && lane < 32) {
            *(float4*)&u.wp[it & 1][w][4 * mI] = make_float4(sp[0], sp[1], sp[2], sp[3]);
        }
        __syncthreads();   // the ONLY barrier per iteration (wp double-buffered)
        {
            float4 s0 = *(const float4*)&u.wp[it & 1][0][4*mI];
            float4 s1 = *(const float4*)&u.wp[it & 1][1][4*mI];
            float4 s2 = *(const float4*)&u.wp[it & 1][2][4*mI];
            float4 s3 = *(const float4*)&u.wp[it & 1][3][4*mI];
            float4 s4 = *(const float4*)&u.wp[it & 1][4][4*mI];
            float4 s5 = *(const float4*)&u.wp[it & 1][5][4*mI];
            float4 s6 = *(const float4*)&u.wp[it & 1][6][4*mI];
            float t0 = s0.x+s1.x+s2.x+s3.x+s4.x+s5.x+s6.x;
            float t1 = s0.y+s1.y+s2.y+s3.y+s4.y+s5.y+s6.y;
            float t2 = s0.z+s1.z+s2.z+s3.z+s4.z+s5.z+s6.z;
            float t3 = s0.w+s1.w+s2.w+s3.w+s4.w+s5.w+s6.w;
            sg[0] = __builtin_amdgcn_rcpf(xlen*t0 + xmv[0]);
            sg[1] = __builtin_amdgcn_rcpf(xlen*t1 + xmv[1]);
            sg[2] = __builtin_amdgcn_rcpf(xlen*t2 + xmv[2]);
            sg[3] = __builtin_amdgcn_rcpf(xlen*t3 + xmv[3]);
        }
        if (it < ITERS - 1) {
#pragma unroll
            for (int j = 0; j < 8; j++) {
                float dj = dl[j];
#pragma unroll
                for (int i = 0; i < 4; i++)
                    qq[j][i] = (qq[j][i] * aa[j][i]) * (dj * sg[i]);
            }
        }
    }

    // ot = sum C^T (.) T_50 ;  c = -0.5*ln(a) on non-pad entries
    float local = 0.0f;
#pragma unroll
    for (int j = 0; j < 8; j++)
#pragma unroll
        for (int i = 0; i < 4; i++) {
            float av = aa[j][i];
            float cc = (av > 0.0f) ? (-0.5f * logf(av)) : 0.0f;
            local += cc * qq[j][i] * (dl[j] * sg[i]);
        }
    local = xorsum32(local);
    local += __shfl_xor(local, 32);
    if (lane == 0) red[w] = local;
    __syncthreads();
    if (t == 0) {
        float tot = red[0] + red[1] + red[2] + red[3] + red[4] + red[5] + red[6] + red[7];
        float sgn = (is_correct[b] == 1) ? 1.0f : -1.0f;
        atomicAdd(out, sgn * tot / (float)nblocks);
    }
}

extern "C" void kernel_launch(void* const* d_in, const int* in_sizes, int n_in,
                              void* d_out, int out_size, void* d_ws, size_t ws_size,
                              hipStream_t stream) {
    const float* seq   = (const float*)d_in[0];
    const int* txt_pad = (const int*)d_in[3];
    const int* img_pad = (const int*)d_in[4];
    const int* is_corr = (const int*)d_in[5];
    float* out = (float*)d_out;
    const int B = in_sizes[5];

    hipMemsetAsync(out, 0, sizeof(float), stream);
    WRA_ot_kernel<<<B, NT, 0, stream>>>(seq, txt_pad, img_pad, is_corr, out, B);
}